// Round 2
// baseline (336.861 us; speedup 1.0000x reference)
//
#include <hip/hip_runtime.h>

#define T_TOK 2048
#define DIM   512
#define MOE   256
#define NE    64
#define NG    8
#define TOPKG 4
#define TOPK  8
#define CAP   1024
#define MOE_SCALE 2.5f

typedef float f32x4 __attribute__((ext_vector_type(4)));
typedef short s16x8 __attribute__((ext_vector_type(8)));

__device__ __forceinline__ unsigned short f2bf(float f) {
    unsigned u = __builtin_bit_cast(unsigned, f);
    unsigned r = (u + 0x7fffu + ((u >> 16) & 1u)) >> 16;
    return (unsigned short)r;
}

// ---------------- Gating stage 1: scores = sigmoid(x @ gate_w^T) ----------------
__global__ __launch_bounds__(256) void gate_scores_k(const float* __restrict__ x,
                                                     const float* __restrict__ gw,
                                                     float* __restrict__ scores)
{
    int t = blockIdx.x * 4 + (threadIdx.x >> 6);
    int e = threadIdx.x & 63;
    const float4* xr = (const float4*)(x + (size_t)t * DIM);
    const float4* wr = (const float4*)(gw + (size_t)e * DIM);
    float acc = 0.f;
#pragma unroll 8
    for (int i = 0; i < DIM / 4; ++i) {
        float4 xa = xr[i], wa = wr[i];
        acc += xa.x * wa.x + xa.y * wa.y + xa.z * wa.z + xa.w * wa.w;
    }
    scores[t * NE + e] = 1.f / (1.f + __expf(-acc));
}

// ---------------- Gating stage 2: grouped top-k + dispatch lists ----------------
__global__ __launch_bounds__(256) void gate_topk_k(const float* __restrict__ scores,
                                                   const float* __restrict__ gb,
                                                   int* __restrict__ counts,
                                                   int* __restrict__ etok,
                                                   float* __restrict__ ewt)
{
    int t = blockIdx.x * 256 + threadIdx.x;
    if (t >= T_TOK) return;
    float sc[NE], s[NE];
    for (int e = 0; e < NE; ++e) {
        sc[e] = scores[t * NE + e];
        s[e] = sc[e] + gb[e];
    }
    float gs[NG];
    for (int g = 0; g < NG; ++g) {
        float m1 = -1e30f, m2 = -1e30f;
        for (int j = 0; j < 8; ++j) {
            float v = s[g * 8 + j];
            if (v > m1) { m2 = m1; m1 = v; }
            else if (v > m2) { m2 = v; }
        }
        gs[g] = m1 + m2;
    }
    bool gsel[NG];
    for (int g = 0; g < NG; ++g) gsel[g] = false;
    for (int k = 0; k < TOPKG; ++k) {
        float best = -2e30f; int bi = 0;
        for (int g = 0; g < NG; ++g)
            if (!gsel[g] && gs[g] > best) { best = gs[g]; bi = g; }
        gsel[bi] = true;
    }
    for (int g = 0; g < NG; ++g)
        if (!gsel[g])
            for (int j = 0; j < 8; ++j) s[g * 8 + j] = -1e30f;
    int idx[TOPK]; float wv[TOPK]; float wsum = 0.f;
    for (int k = 0; k < TOPK; ++k) {
        float best = -2e30f; int bi = 0;
        for (int e = 0; e < NE; ++e)
            if (s[e] > best) { best = s[e]; bi = e; }
        s[bi] = -2e30f;
        idx[k] = bi; wv[k] = sc[bi]; wsum += sc[bi];
    }
    float scale = MOE_SCALE / wsum;
    for (int k = 0; k < TOPK; ++k) {
        int e = idx[k];
        int p = atomicAdd(&counts[e], 1);
        if (p < CAP) {
            etok[e * CAP + p] = t;
            ewt[e * CAP + p] = wv[k] * scale;
        }
    }
}

// ---------------- FFN grouped GEMM ----------------
// Per wave: GEMM over a 64-col slice of W (fp32 row-major [Kd][ldw], k-strided
// for the B operand). Stages 32x32 tiles transposed + converted to bf16
// pair-packed dwords in wave-private LDS so B-frags are single ds_read_b128.
__device__ __forceinline__ void wave_gemm64(const short* Albase, int lda,
                                            const float* W, int ldw, int Kd,
                                            int n0, int lane, int* Btw,
                                            f32x4 acc[2][4])
{
    int q = lane >> 4, m16 = lane & 15;
    for (int k0 = 0; k0 < Kd; k0 += 32) {
        s16x8 a0 = *(const s16x8*)(Albase + (m16) * lda + k0 + q * 8);
        s16x8 a1 = *(const s16x8*)(Albase + (16 + m16) * lda + k0 + q * 8);
#pragma unroll
        for (int h = 0; h < 2; ++h) {
            const float* Wg = W + (size_t)k0 * ldw + n0 + h * 32;
#pragma unroll
            for (int i = 0; i < 4; ++i) {
                int task = i * 64 + lane;     // 256 tasks: 16 n-pairs x 16 k-pairs
                int np = task & 15;
                int kp = task >> 4;
                const float* src = Wg + (size_t)(2 * kp) * ldw + 2 * np;
                float2 r0 = *(const float2*)src;          // W[2kp][2np..2np+1]
                float2 r1 = *(const float2*)(src + ldw);  // W[2kp+1][2np..2np+1]
                // Bt[n][kp] dword = (bf16 W[k][n], bf16 W[k+1][n])
                Btw[(2 * np) * 20 + kp]     = (unsigned)f2bf(r0.x) | ((unsigned)f2bf(r1.x) << 16);
                Btw[(2 * np + 1) * 20 + kp] = (unsigned)f2bf(r0.y) | ((unsigned)f2bf(r1.y) << 16);
            }
#pragma unroll
            for (int nt = 0; nt < 2; ++nt) {
                s16x8 b = *(const s16x8*)&Btw[(nt * 16 + m16) * 20 + q * 4];
                int fi = h * 2 + nt;
                acc[0][fi] = __builtin_amdgcn_mfma_f32_16x16x32_bf16(a0, b, acc[0][fi], 0, 0, 0);
                acc[1][fi] = __builtin_amdgcn_mfma_f32_16x16x32_bf16(a1, b, acc[1][fi], 0, 0, 0);
            }
        }
    }
}

__global__ __launch_bounds__(256) void ffn_kernel(const float* __restrict__ x,
                                                  const float* __restrict__ w1,
                                                  const float* __restrict__ w3,
                                                  const float* __restrict__ w2,
                                                  const int* __restrict__ counts,
                                                  const int* __restrict__ etok,
                                                  const float* __restrict__ ewt,
                                                  float* __restrict__ out)
{
    __shared__ short Xa[32 * 520];        // 32 tokens x 512 bf16, stride 520
    __shared__ short Ht[32 * 264];        // 32 tokens x 256 bf16, stride 264
    __shared__ int   Bt[4][32 * 20];      // per-wave transposed B staging
    __shared__ int   tok_s[32];
    __shared__ float wt_s[32];

    int e    = blockIdx.x & 63;
    int tile = blockIdx.x >> 6;
    int n_e  = min(counts[e], CAP);
    int r0   = tile * 32;
    if (r0 >= n_e) return;
    int nrows = min(32, n_e - r0);

    int tid = threadIdx.x;
    if (tid < 32) {
        if (tid < nrows) {
            tok_s[tid] = etok[e * CAP + r0 + tid];
            wt_s[tid]  = ewt[e * CAP + r0 + tid];
        } else { tok_s[tid] = 0; wt_s[tid] = 0.f; }
    }
    {
        // 8 threads per token row; each converts 64 fp32 -> 64 bf16
        int r = tid >> 3, c = tid & 7;
        short* dst = Xa + r * 520 + c * 64;
        if (r < nrows) {
            int tok = etok[e * CAP + r0 + r];
            const float4* src = (const float4*)(x + (size_t)tok * DIM + c * 64);
#pragma unroll
            for (int i = 0; i < 16; ++i) {
                float4 f = src[i];
                short4 o;
                o.x = (short)f2bf(f.x); o.y = (short)f2bf(f.y);
                o.z = (short)f2bf(f.z); o.w = (short)f2bf(f.w);
                *(short4*)(dst + i * 4) = o;
            }
        } else {
            short4 z = {0, 0, 0, 0};
#pragma unroll
            for (int i = 0; i < 16; ++i) *(short4*)(dst + i * 4) = z;
        }
    }
    __syncthreads();

    int w = tid >> 6, lane = tid & 63;
    int q = lane >> 4, m16 = lane & 15;
    int* Btw = Bt[w];

    f32x4 acc1[2][4], acc3[2][4];
#pragma unroll
    for (int i = 0; i < 2; ++i)
#pragma unroll
        for (int j = 0; j < 4; ++j) { acc1[i][j] = (f32x4)0.f; acc3[i][j] = (f32x4)0.f; }

    const size_t eoff = (size_t)e * DIM * MOE;
    wave_gemm64(Xa, 520, w1 + eoff, MOE, DIM, w * 64, lane, Btw, acc1);
    wave_gemm64(Xa, 520, w3 + eoff, MOE, DIM, w * 64, lane, Btw, acc3);

    // SwiGLU -> Ht (bf16)
#pragma unroll
    for (int mt = 0; mt < 2; ++mt)
#pragma unroll
        for (int nt = 0; nt < 4; ++nt)
#pragma unroll
            for (int r = 0; r < 4; ++r) {
                float g = acc1[mt][nt][r];
                float u = acc3[mt][nt][r];
                float hv = g / (1.f + __expf(-g)) * u;
                int t = mt * 16 + q * 4 + r;
                int m = w * 64 + nt * 16 + m16;
                Ht[t * 264 + m] = (short)f2bf(hv);
            }
    __syncthreads();

    // GEMM2: Y = H @ W2, wave handles 128 output cols in two 64-col halves
    for (int h2 = 0; h2 < 2; ++h2) {
        f32x4 acc2[2][4];
#pragma unroll
        for (int i = 0; i < 2; ++i)
#pragma unroll
            for (int j = 0; j < 4; ++j) acc2[i][j] = (f32x4)0.f;
        int n0 = w * 128 + h2 * 64;
        wave_gemm64(Ht, 264, w2 + (size_t)e * MOE * DIM, DIM, MOE, n0, lane, Btw, acc2);
#pragma unroll
        for (int mt = 0; mt < 2; ++mt)
#pragma unroll
            for (int nt = 0; nt < 4; ++nt)
#pragma unroll
                for (int r = 0; r < 4; ++r) {
                    int t = mt * 16 + q * 4 + r;
                    if (t < nrows) {
                        int d = n0 + nt * 16 + m16;
                        float v = acc2[mt][nt][r] * wt_s[t];
                        atomicAdd(out + (size_t)tok_s[t] * DIM + d, v);
                    }
                }
    }
}

extern "C" void kernel_launch(void* const* d_in, const int* in_sizes, int n_in,
                              void* d_out, int out_size, void* d_ws, size_t ws_size,
                              hipStream_t stream)
{
    const float* x  = (const float*)d_in[0];
    const float* gw = (const float*)d_in[1];
    const float* gb = (const float*)d_in[2];
    const float* w1 = (const float*)d_in[3];
    const float* w3 = (const float*)d_in[4];
    const float* w2 = (const float*)d_in[5];

    char* ws = (char*)d_ws;
    float* scores = (float*)(ws);                    // 2048*64*4 = 524,288
    int*   etok   = (int*)  (ws + 524288);           // 64*1024*4 = 262,144
    float* ewt    = (float*)(ws + 786432);           // 64*1024*4 = 262,144
    int*   counts = (int*)  (ws + 1048576);          // 64*4

    hipMemsetAsync(d_out, 0, (size_t)out_size * 4, stream);
    hipMemsetAsync(counts, 0, NE * 4, stream);

    gate_scores_k<<<T_TOK / 4, 256, 0, stream>>>(x, gw, scores);
    gate_topk_k<<<T_TOK / 256, 256, 0, stream>>>(scores, gb, counts, etok, ewt);
    ffn_kernel<<<NE * (CAP / 32), 256, 0, stream>>>(x, w1, w3, w2, counts, etok, ewt,
                                                    (float*)d_out);
}